// Round 2
// baseline (2422.713 us; speedup 1.0000x reference)
//
#include <hip/hip_runtime.h>
#include <cstdint>
#include <cstddef>

// LIF cell: new_v = DECAY*v0 + (1-DECAY)*([inputs|z0] @ [w_in; w_rec_nd]) - z0
// then spike/refractory. B=4096, K=8192, N=4096.
// d_out dtype: float32 (reference outputs are f32/int32 -> "else float*").
// GEMM precision: 2-way f16 split (hi + lo/1024) for both operands ->
// f32-equivalent accuracy at f16 MFMA rate x3 passes (x2 for the z0 half,
// whose lo-part is exactly zero). Weights pre-scaled x256 to keep their
// lo-parts in f16 normal range.

typedef __attribute__((ext_vector_type(8))) _Float16 f16x8;
typedef __attribute__((ext_vector_type(4))) float f32x4;

#define DECAY_F 0.9512294245007140f
#define ONEMD_F 0.0487705754992860f
#define KTOT 8192
#define BK 32
#define LDP 36  // padded LDS stride (f16 elems): 72B = 18 banks, 16 rows distinct mod 32

// ---------------------------------------------------------------------------
// Prepass: WtH/WtL[n][k] = f16 split of 256 * (k<4096 ? w_in[k][n]
//                            : (k-4096==n ? 0 : w_rec[k-4096][n]))
// ---------------------------------------------------------------------------
__global__ __launch_bounds__(256) void prep_w(const float* __restrict__ w_in,
                                              const float* __restrict__ w_rec,
                                              _Float16* __restrict__ wtH,
                                              _Float16* __restrict__ wtL) {
  __shared__ float s[64][65];
  int bid = blockIdx.x;
  int kt = bid >> 6;   // 0..127
  int nt = bid & 63;   // 0..63
  int k0 = kt * 64, n0 = nt * 64;
  int t = threadIdx.x;

  bool rec = (k0 >= 4096);
  const float* W = rec ? w_rec : w_in;
  int kb = rec ? (k0 - 4096) : k0;

  int cr = t >> 4;          // 0..15
  int cc = (t & 15) * 4;    // 0..60
#pragma unroll
  for (int j = 0; j < 4; ++j) {
    int r = cr + j * 16;
    float4 v = *reinterpret_cast<const float4*>(&W[(size_t)(kb + r) * 4096 + n0 + cc]);
    s[r][cc + 0] = v.x; s[r][cc + 1] = v.y; s[r][cc + 2] = v.z; s[r][cc + 3] = v.w;
  }
  __syncthreads();
#pragma unroll
  for (int j = 0; j < 2; ++j) {
    int g = t + 256 * j;      // 0..511
    int n = g >> 3;           // 0..63
    int k8 = (g & 7) * 8;     // 0..56
    f16x8 h, l;
#pragma unroll
    for (int i = 0; i < 8; ++i) {
      float w = s[k8 + i][n];
      int gk = k0 + k8 + i;
      if (rec && (gk - 4096) == (n0 + n)) w = 0.0f;  // diagonal disconnect
      w *= 256.0f;
      _Float16 hi = (_Float16)w;
      h[i] = hi;
      l[i] = (_Float16)((w - (float)hi) * 1024.0f);
    }
    size_t o = (size_t)(n0 + n) * KTOT + (size_t)(k0 + k8);
    *reinterpret_cast<f16x8*>(&wtH[o]) = h;
    *reinterpret_cast<f16x8*>(&wtL[o]) = l;
  }
}

// ---------------------------------------------------------------------------
// Fused split-GEMM + LIF epilogue. 128x128 tile, BK=32, 4 waves (2x2).
// ---------------------------------------------------------------------------
__global__ __launch_bounds__(256) void lif_gemm(const float* __restrict__ inputs,
                                                const float* __restrict__ v0,
                                                const int* __restrict__ r0,
                                                const float* __restrict__ z0,
                                                const _Float16* __restrict__ wtH,
                                                const _Float16* __restrict__ wtL,
                                                float* __restrict__ outv,
                                                float* __restrict__ outz,
                                                float* __restrict__ outr) {
  __shared__ _Float16 sAh[128][LDP];
  __shared__ _Float16 sAl[128][LDP];
  __shared__ _Float16 sBh[128][LDP];
  __shared__ _Float16 sBl[128][LDP];

  int bid = blockIdx.x;
  int swz = (bid & 7) * 128 + (bid >> 3);  // XCD swizzle, bijective (1024%8==0)
  int bm = swz >> 5, bn = swz & 31;
  int row0 = bm * 128;   // batch rows
  int col0 = bn * 128;   // neuron cols

  int t = threadIdx.x;
  int w = t >> 6, lane = t & 63;
  int wr = w >> 1, wc = w & 1;

  f32x4 accH[4][4], accL[4][4];
#pragma unroll
  for (int i = 0; i < 4; ++i)
#pragma unroll
    for (int j = 0; j < 4; ++j) {
      accH[i][j] = (f32x4){0.f, 0.f, 0.f, 0.f};
      accL[i][j] = (f32x4){0.f, 0.f, 0.f, 0.f};
    }

  for (int k0 = 0; k0 < KTOT; k0 += BK) {
    bool inHalf = (k0 < 4096);
    const float* Abase = inHalf ? inputs : z0;
    int kA = inHalf ? k0 : (k0 - 4096);

    // ---- stage A (f32 -> hi/lo f16)
#pragma unroll
    for (int j = 0; j < 2; ++j) {
      int g = t + 256 * j;        // 0..511
      int m = g >> 2;             // 0..127
      int kk8 = (g & 3) * 8;      // 0,8,16,24
      const float4* p = reinterpret_cast<const float4*>(&Abase[(size_t)(row0 + m) * 4096 + kA + kk8]);
      float4 x = p[0], y = p[1];
      float xs[8] = {x.x, x.y, x.z, x.w, y.x, y.y, y.z, y.w};
      f16x8 h, l;
#pragma unroll
      for (int i = 0; i < 8; ++i) {
        _Float16 hi = (_Float16)xs[i];
        h[i] = hi;
        l[i] = (_Float16)((xs[i] - (float)hi) * 1024.0f);
      }
      *reinterpret_cast<f16x8*>(&sAh[m][kk8]) = h;
      if (inHalf) *reinterpret_cast<f16x8*>(&sAl[m][kk8]) = l;  // z0-half lo == 0
    }
    // ---- stage B (preconverted f16 planes)
#pragma unroll
    for (int j = 0; j < 2; ++j) {
      int g = t + 256 * j;
      int n = g >> 2;
      int kk8 = (g & 3) * 8;
      size_t o = (size_t)(col0 + n) * KTOT + (size_t)(k0 + kk8);
      *reinterpret_cast<f16x8*>(&sBh[n][kk8]) = *reinterpret_cast<const f16x8*>(&wtH[o]);
      *reinterpret_cast<f16x8*>(&sBl[n][kk8]) = *reinterpret_cast<const f16x8*>(&wtL[o]);
    }
    __syncthreads();

    // ---- MFMA: accH += hiA*hiB ; accL += hiA*loB (+ loA*hiB when A has lo)
    int kk = (lane >> 4) * 8;
    int rl = lane & 15;
    f16x8 ah[4], al[4];
#pragma unroll
    for (int i = 0; i < 4; ++i)
      ah[i] = *reinterpret_cast<const f16x8*>(&sAh[wr * 64 + i * 16 + rl][kk]);
    if (inHalf) {
#pragma unroll
      for (int i = 0; i < 4; ++i)
        al[i] = *reinterpret_cast<const f16x8*>(&sAl[wr * 64 + i * 16 + rl][kk]);
    }
#pragma unroll
    for (int ni = 0; ni < 4; ++ni) {
      f16x8 bh = *reinterpret_cast<const f16x8*>(&sBh[wc * 64 + ni * 16 + rl][kk]);
      f16x8 bl = *reinterpret_cast<const f16x8*>(&sBl[wc * 64 + ni * 16 + rl][kk]);
#pragma unroll
      for (int mi = 0; mi < 4; ++mi) {
        accH[mi][ni] = __builtin_amdgcn_mfma_f32_16x16x32_f16(ah[mi], bh, accH[mi][ni], 0, 0, 0);
        accL[mi][ni] = __builtin_amdgcn_mfma_f32_16x16x32_f16(ah[mi], bl, accL[mi][ni], 0, 0, 0);
      }
      if (inHalf) {
#pragma unroll
        for (int mi = 0; mi < 4; ++mi)
          accL[mi][ni] = __builtin_amdgcn_mfma_f32_16x16x32_f16(al[mi], bh, accL[mi][ni], 0, 0, 0);
      }
    }
    __syncthreads();
  }

  // ---- LIF epilogue (C/D: col = lane&15, row = (lane>>4)*4 + reg)
  const float invW = 1.0f / 256.0f;
  const float invL = 1.0f / 1024.0f;
  int colL = col0 + wc * 64 + (lane & 15);
  int rowB = row0 + wr * 64 + ((lane >> 4) << 2);
#pragma unroll
  for (int mi = 0; mi < 4; ++mi) {
#pragma unroll
    for (int ni = 0; ni < 4; ++ni) {
      int n = colL + ni * 16;
#pragma unroll
      for (int j = 0; j < 4; ++j) {
        int b = rowB + mi * 16 + j;
        size_t idx = (size_t)b * 4096 + n;
        float S = (accH[mi][ni][j] + accL[mi][ni][j] * invL) * invW;
        float z0v = z0[idx];
        float v0v = v0[idx];
        int r0v = r0[idx];
        float v = DECAY_F * v0v + (ONEMD_F * S - z0v);
        bool spike = (v > 1.0f) && (r0v <= 0);
        int rr = r0v - 1 + (spike ? 5 : 0);
        rr = rr < 0 ? 0 : (rr > 5 ? 5 : rr);
        outv[idx] = v;
        outz[idx] = spike ? 1.0f : 0.0f;
        outr[idx] = (float)rr;
      }
    }
  }
}

// ---------------------------------------------------------------------------
extern "C" void kernel_launch(void* const* d_in, const int* in_sizes, int n_in,
                              void* d_out, int out_size, void* d_ws, size_t ws_size,
                              hipStream_t stream) {
  const float* inputs = (const float*)d_in[0];
  const float* v0     = (const float*)d_in[1];
  const int*   r0     = (const int*)d_in[2];
  const float* z0     = (const float*)d_in[3];
  const float* w_in   = (const float*)d_in[4];
  const float* w_rec  = (const float*)d_in[5];

  const size_t plane = (size_t)4096 * KTOT;  // elements per f16 plane
  if (ws_size < plane * 2 * sizeof(_Float16)) return;  // need 128 MB

  _Float16* wtH = (_Float16*)d_ws;
  _Float16* wtL = wtH + plane;

  float* out  = (float*)d_out;
  float* outv = out;
  float* outz = out + (size_t)4096 * 4096;
  float* outr = out + (size_t)2 * 4096 * 4096;

  prep_w<<<dim3(8192), dim3(256), 0, stream>>>(w_in, w_rec, wtH, wtL);
  lif_gemm<<<dim3(1024), dim3(256), 0, stream>>>(inputs, v0, r0, z0, wtH, wtL,
                                                 outv, outz, outr);
}

// Round 3
// 1042.249 us; speedup vs baseline: 2.3245x; 2.3245x over previous
//
#include <hip/hip_runtime.h>
#include <cstdint>
#include <cstddef>

// LIF cell: new_v = DECAY*v0 + (1-DECAY)*([inputs|z0] @ [w_in; w_rec_nd]) - z0
// B=4096, K=8192, N=4096. Outputs f32 (v, z, r).
// Precision: 2-way f16 split GEMM (hi + lo/1024), weights pre-scaled x256.
// Passes: aH.wH (K=8192) -> accH ; aH.wL (8192) + aL.wH (4096) -> accL.
// S = (accH + accL/1024)/256.
//
// Buffers: ws = wtH(64MB) | wtL(64MB).  aH lives in outz plane (64MB),
// aL in outr plane (32MB) -- scratch until the final epilogue kernel
// overwrites them.  GEMM writes raw S into outv plane.

typedef __attribute__((ext_vector_type(8))) _Float16 f16x8;
typedef __attribute__((ext_vector_type(4))) float f32x4;

#define DECAY_F 0.9512294245007140f
#define ONEMD_F 0.0487705754992860f
#define KW 8192

// global->LDS direct copy, 16 B per lane; dest must be wave-uniform base.
__device__ __forceinline__ void gl2lds16(const void* g, void* s) {
  __builtin_amdgcn_global_load_lds(
      (const __attribute__((address_space(1))) uint32_t*)g,
      (__attribute__((address_space(3))) uint32_t*)s, 16, 0, 0);
}

// swizzled LDS fragment pointer: linear [128][64]f16 rows (128 B), read col
// XORed by (row&7)<<4 to match the pre-swizzled staging source.
__device__ __forceinline__ const f16x8* ldsfrag(const _Float16* base, int row, int kk) {
  int byte = (row << 7) + (((kk << 1)) ^ ((row & 7) << 4));
  return (const f16x8*)((const char*)base + byte);
}

// ---------------------------------------------------------------------------
// prep_w: WtH/WtL[n][k] = f16 split of 256 * (k<4096 ? w_in[k][n]
//                          : (k-4096==n ? 0 : w_rec[k-4096][n]))
// ---------------------------------------------------------------------------
__global__ __launch_bounds__(256) void prep_w(const float* __restrict__ w_in,
                                              const float* __restrict__ w_rec,
                                              _Float16* __restrict__ wtH,
                                              _Float16* __restrict__ wtL) {
  __shared__ float s[64][65];
  int bid = blockIdx.x;
  int kt = bid >> 6, nt = bid & 63;
  int k0 = kt * 64, n0 = nt * 64;
  int t = threadIdx.x;

  bool rec = (k0 >= 4096);
  const float* W = rec ? w_rec : w_in;
  int kb = rec ? (k0 - 4096) : k0;

  int cr = t >> 4;
  int cc = (t & 15) * 4;
#pragma unroll
  for (int j = 0; j < 4; ++j) {
    int r = cr + j * 16;
    float4 v = *reinterpret_cast<const float4*>(&W[(size_t)(kb + r) * 4096 + n0 + cc]);
    s[r][cc + 0] = v.x; s[r][cc + 1] = v.y; s[r][cc + 2] = v.z; s[r][cc + 3] = v.w;
  }
  __syncthreads();
#pragma unroll
  for (int j = 0; j < 2; ++j) {
    int g = t + 256 * j;
    int n = g >> 3;
    int k8 = (g & 7) * 8;
    f16x8 h, l;
#pragma unroll
    for (int i = 0; i < 8; ++i) {
      float w = s[k8 + i][n];
      int gk = k0 + k8 + i;
      if (rec && (gk - 4096) == (n0 + n)) w = 0.0f;
      w *= 256.0f;
      _Float16 hi = (_Float16)w;
      h[i] = hi;
      l[i] = (_Float16)((w - (float)hi) * 1024.0f);
    }
    size_t o = (size_t)(n0 + n) * KW + (size_t)(k0 + k8);
    *reinterpret_cast<f16x8*>(&wtH[o]) = h;
    *reinterpret_cast<f16x8*>(&wtL[o]) = l;
  }
}

// ---------------------------------------------------------------------------
// prep_a: aH[b][0:4096]=f16(inputs), aH[b][4096:8192]=f16(z0) (exact),
//         aL[b][0:4096]=f16((inputs-hi)*1024)
// ---------------------------------------------------------------------------
__global__ __launch_bounds__(256) void prep_a(const float* __restrict__ inputs,
                                              const float* __restrict__ z0,
                                              _Float16* __restrict__ aH,
                                              _Float16* __restrict__ aL) {
  int g = blockIdx.x * 256 + threadIdx.x;  // 0 .. 2M-1
  int b = g >> 9;
  int k8 = (g & 511) * 8;

  const float4* pi = reinterpret_cast<const float4*>(&inputs[(size_t)b * 4096 + k8]);
  float4 x = pi[0], y = pi[1];
  float xs[8] = {x.x, x.y, x.z, x.w, y.x, y.y, y.z, y.w};
  f16x8 h, l;
#pragma unroll
  for (int i = 0; i < 8; ++i) {
    _Float16 hi = (_Float16)xs[i];
    h[i] = hi;
    l[i] = (_Float16)((xs[i] - (float)hi) * 1024.0f);
  }
  *reinterpret_cast<f16x8*>(&aH[(size_t)b * 8192 + k8]) = h;
  *reinterpret_cast<f16x8*>(&aL[(size_t)b * 4096 + k8]) = l;

  const float4* pz = reinterpret_cast<const float4*>(&z0[(size_t)b * 4096 + k8]);
  x = pz[0]; y = pz[1];
  float zs[8] = {x.x, x.y, x.z, x.w, y.x, y.y, y.z, y.w};
  f16x8 hz;
#pragma unroll
  for (int i = 0; i < 8; ++i) hz[i] = (_Float16)zs[i];
  *reinterpret_cast<f16x8*>(&aH[(size_t)b * 8192 + 4096 + k8]) = hz;
}

// ---------------------------------------------------------------------------
// lif_gemm: pure split-GEMM -> S (f32) into outv plane.
// 128x128 tile, BK=64, 4 waves (2x2), 320 K-steps (3 segments).
// LDS linear [128][64]f16 per operand, staged via global_load_lds with
// pre-swizzled source; ds_read col XOR (row&7)<<4.
// ---------------------------------------------------------------------------
__global__ __launch_bounds__(256, 2) void lif_gemm(const _Float16* __restrict__ aH,
                                                   const _Float16* __restrict__ aL,
                                                   const _Float16* __restrict__ wtH,
                                                   const _Float16* __restrict__ wtL,
                                                   float* __restrict__ Sout) {
  __shared__ _Float16 sA[128 * 64];
  __shared__ _Float16 sB[128 * 64];

  int bid = blockIdx.x;
  int swz = (bid & 7) * 128 + (bid >> 3);  // XCD swizzle (1024 % 8 == 0)
  int bm = swz >> 5, bn = swz & 31;
  int row0 = bm * 128;
  int col0 = bn * 128;

  int t = threadIdx.x;
  int w = t >> 6, lane = t & 63;
  int wr = w >> 1, wc = w & 1;

  f32x4 accH[4][4], accL[4][4];
#pragma unroll
  for (int i = 0; i < 4; ++i)
#pragma unroll
    for (int j = 0; j < 4; ++j) {
      accH[i][j] = (f32x4){0.f, 0.f, 0.f, 0.f};
      accL[i][j] = (f32x4){0.f, 0.f, 0.f, 0.f};
    }

  // per-lane staging geometry (constant across steps)
  const int lrow = lane >> 3;               // 0..7 within 8-row chunk
  const int sc = (lane & 7) ^ lrow;         // swizzled 16B source chunk
  const int rbase = w << 2;                 // wave's first chunk (4 per wave)

  for (int step = 0; step < 320; ++step) {
    const _Float16* aP;
    const _Float16* wP;
    int kb, aStr;
    bool toH;
    if (step < 128)      { aP = aH; wP = wtH; kb = step << 6;         aStr = 8192; toH = true;  }
    else if (step < 256) { aP = aH; wP = wtL; kb = (step - 128) << 6; aStr = 8192; toH = false; }
    else                 { aP = aL; wP = wtH; kb = (step - 256) << 6; aStr = 4096; toH = false; }

    __syncthreads();  // previous compute done before overwriting LDS
#pragma unroll
    for (int i = 0; i < 4; ++i) {
      int chunk = rbase + i;                 // 0..15
      int row = (chunk << 3) + lrow;         // 0..127
      const char* src = (const char*)aP +
          ((((size_t)(row0 + row)) * aStr + kb) << 1) + (sc << 4);
      gl2lds16(src, (char*)sA + (chunk << 10));
    }
#pragma unroll
    for (int i = 0; i < 4; ++i) {
      int chunk = rbase + i;
      int row = (chunk << 3) + lrow;
      const char* src = (const char*)wP +
          ((((size_t)(col0 + row)) * 8192 + kb) << 1) + (sc << 4);
      gl2lds16(src, (char*)sB + (chunk << 10));
    }
    __syncthreads();  // drains vmcnt -> LDS tiles ready

    const int rl = lane & 15;
#pragma unroll
    for (int ks = 0; ks < 2; ++ks) {
      const int kk = ks * 32 + ((lane >> 4) << 3);
      f16x8 av[4], bv[4];
#pragma unroll
      for (int i = 0; i < 4; ++i) {
        av[i] = *ldsfrag(sA, wr * 64 + i * 16 + rl, kk);
        bv[i] = *ldsfrag(sB, wc * 64 + i * 16 + rl, kk);
      }
      if (toH) {
#pragma unroll
        for (int mi = 0; mi < 4; ++mi)
#pragma unroll
          for (int ni = 0; ni < 4; ++ni)
            accH[mi][ni] = __builtin_amdgcn_mfma_f32_16x16x32_f16(av[mi], bv[ni], accH[mi][ni], 0, 0, 0);
      } else {
#pragma unroll
        for (int mi = 0; mi < 4; ++mi)
#pragma unroll
          for (int ni = 0; ni < 4; ++ni)
            accL[mi][ni] = __builtin_amdgcn_mfma_f32_16x16x32_f16(av[mi], bv[ni], accL[mi][ni], 0, 0, 0);
      }
    }
  }

  // write raw S (C/D: col = lane&15, row = (lane>>4)*4 + j)
  const float invW = 1.0f / 256.0f;
  const float invL = 1.0f / 1024.0f;
  int colL = col0 + wc * 64 + (lane & 15);
  int rowB = row0 + wr * 64 + ((lane >> 4) << 2);
#pragma unroll
  for (int mi = 0; mi < 4; ++mi)
#pragma unroll
    for (int ni = 0; ni < 4; ++ni) {
      int n = colL + ni * 16;
#pragma unroll
      for (int j = 0; j < 4; ++j) {
        int b = rowB + mi * 16 + j;
        Sout[(size_t)b * 4096 + n] =
            (accH[mi][ni][j] + accL[mi][ni][j] * invL) * invW;
      }
    }
}

// ---------------------------------------------------------------------------
// epilogue: elementwise LIF update. S is read from outv plane (in place).
// ---------------------------------------------------------------------------
__global__ __launch_bounds__(256) void lif_epilogue(const float* __restrict__ v0,
                                                    const int* __restrict__ r0,
                                                    const float* __restrict__ z0,
                                                    float* __restrict__ outv,
                                                    float* __restrict__ outz,
                                                    float* __restrict__ outr) {
  size_t i = ((size_t)blockIdx.x * 256 + threadIdx.x) * 4;
  float4 S = *reinterpret_cast<const float4*>(&outv[i]);
  float4 V = *reinterpret_cast<const float4*>(&v0[i]);
  float4 Z = *reinterpret_cast<const float4*>(&z0[i]);
  int4 R = *reinterpret_cast<const int4*>(&r0[i]);
  float s[4] = {S.x, S.y, S.z, S.w};
  float v[4] = {V.x, V.y, V.z, V.w};
  float z[4] = {Z.x, Z.y, Z.z, Z.w};
  int r[4] = {R.x, R.y, R.z, R.w};
  float4 ov, oz, orr;
  float* po[3] = {&ov.x, &oz.x, &orr.x};
#pragma unroll
  for (int j = 0; j < 4; ++j) {
    float nv = DECAY_F * v[j] + (ONEMD_F * s[j] - z[j]);
    bool spike = (nv > 1.0f) && (r[j] <= 0);
    int nr = r[j] - 1 + (spike ? 5 : 0);
    nr = nr < 0 ? 0 : (nr > 5 ? 5 : nr);
    po[0][j] = nv;
    po[1][j] = spike ? 1.0f : 0.0f;
    po[2][j] = (float)nr;
  }
  *reinterpret_cast<float4*>(&outv[i]) = ov;
  *reinterpret_cast<float4*>(&outz[i]) = oz;
  *reinterpret_cast<float4*>(&outr[i]) = orr;
}

// ---------------------------------------------------------------------------
extern "C" void kernel_launch(void* const* d_in, const int* in_sizes, int n_in,
                              void* d_out, int out_size, void* d_ws, size_t ws_size,
                              hipStream_t stream) {
  const float* inputs = (const float*)d_in[0];
  const float* v0     = (const float*)d_in[1];
  const int*   r0     = (const int*)d_in[2];
  const float* z0     = (const float*)d_in[3];
  const float* w_in   = (const float*)d_in[4];
  const float* w_rec  = (const float*)d_in[5];

  const size_t planeW = (size_t)4096 * KW;  // f16 elements per weight plane
  if (ws_size < planeW * 2 * sizeof(_Float16)) return;  // need 128 MB (proven)

  _Float16* wtH = (_Float16*)d_ws;
  _Float16* wtL = wtH + planeW;

  float* out  = (float*)d_out;
  float* outv = out;                               // S, then new_v
  float* outz = out + (size_t)4096 * 4096;         // aH scratch, then new_z
  float* outr = out + (size_t)2 * 4096 * 4096;     // aL scratch, then new_r

  _Float16* aH = (_Float16*)outz;   // [4096][8192] f16 = 64 MB
  _Float16* aL = (_Float16*)outr;   // [4096][4096] f16 = 32 MB

  prep_w<<<dim3(8192), dim3(256), 0, stream>>>(w_in, w_rec, wtH, wtL);
  prep_a<<<dim3(8192), dim3(256), 0, stream>>>(inputs, z0, aH, aL);
  lif_gemm<<<dim3(1024), dim3(256), 0, stream>>>(aH, aL, wtH, wtL, outv);
  lif_epilogue<<<dim3(16384), dim3(256), 0, stream>>>(v0, r0, z0, outv, outz, outr);
}

// Round 4
// 727.515 us; speedup vs baseline: 3.3301x; 1.4326x over previous
//
#include <hip/hip_runtime.h>
#include <cstdint>
#include <cstddef>

// LIF cell: new_v = DECAY*v0 + (1-DECAY)*([inputs|z0] @ [w_in; w_rec_nd]) - z0
// B=4096, K=8192, N=4096. Outputs f32 (v, z, r).
// Precision: 2-way f16 split, UNSCALED residuals -> single accumulator:
//   acc = aH.wH (K 8192) + aH.wL' (8192) + aL'.wH (4096) = 256*S
// GEMM: 256x256 tile, BK=64, 8 waves (2Mx4N), 8-phase-style schedule with
// double-buffered 128KiB LDS, counted vmcnt (never 0 in loop), raw s_barrier,
// setprio around MFMA clusters. 320 K-tiles in one pipelined loop.

typedef __attribute__((ext_vector_type(8))) _Float16 f16x8;
typedef __attribute__((ext_vector_type(4))) float f32x4;

#define DECAY_F 0.9512294245007140f
#define ONEMD_F 0.0487705754992860f

#define BAR() __builtin_amdgcn_s_barrier()
#define WAITV(n) asm volatile("s_waitcnt vmcnt(" #n ")" ::: "memory")

__device__ __forceinline__ void gl2lds16(const void* g, void* s) {
  __builtin_amdgcn_global_load_lds(
      (const __attribute__((address_space(1))) uint32_t*)g,
      (__attribute__((address_space(3))) uint32_t*)s, 16, 0, 0);
}

// ---------------------------------------------------------------------------
// prep_w: WtH[n][k] = f16(256*w), WtL[n][k] = f16(256*w - WtH) (unscaled resid)
// w = k<4096 ? w_in[k][n] : (k-4096==n ? 0 : w_rec[k-4096][n])
// ---------------------------------------------------------------------------
__global__ __launch_bounds__(256) void prep_w(const float* __restrict__ w_in,
                                              const float* __restrict__ w_rec,
                                              _Float16* __restrict__ wtH,
                                              _Float16* __restrict__ wtL) {
  __shared__ float s[64][65];
  int bid = blockIdx.x;
  int kt = bid >> 6, nt = bid & 63;
  int k0 = kt * 64, n0 = nt * 64;
  int t = threadIdx.x;

  bool rec = (k0 >= 4096);
  const float* W = rec ? w_rec : w_in;
  int kb = rec ? (k0 - 4096) : k0;

  int cr = t >> 4;
  int cc = (t & 15) * 4;
#pragma unroll
  for (int j = 0; j < 4; ++j) {
    int r = cr + j * 16;
    float4 v = *reinterpret_cast<const float4*>(&W[(size_t)(kb + r) * 4096 + n0 + cc]);
    s[r][cc + 0] = v.x; s[r][cc + 1] = v.y; s[r][cc + 2] = v.z; s[r][cc + 3] = v.w;
  }
  __syncthreads();
#pragma unroll
  for (int j = 0; j < 2; ++j) {
    int g = t + 256 * j;
    int n = g >> 3;
    int k8 = (g & 7) * 8;
    f16x8 h, l;
#pragma unroll
    for (int i = 0; i < 8; ++i) {
      float w = s[k8 + i][n];
      int gk = k0 + k8 + i;
      if (rec && (gk - 4096) == (n0 + n)) w = 0.0f;
      w *= 256.0f;
      _Float16 hi = (_Float16)w;
      h[i] = hi;
      l[i] = (_Float16)(w - (float)hi);
    }
    size_t o = (size_t)(n0 + n) * 8192 + (size_t)(k0 + k8);
    *reinterpret_cast<f16x8*>(&wtH[o]) = h;
    *reinterpret_cast<f16x8*>(&wtL[o]) = l;
  }
}

// ---------------------------------------------------------------------------
// prep_a: aH[b][0:4096]=f16(inputs), aH[b][4096:8192]=f16(z0) (exact),
//         aL[b][0:4096] = inputs - f16(inputs)  (unscaled residual)
// ---------------------------------------------------------------------------
__global__ __launch_bounds__(256) void prep_a(const float* __restrict__ inputs,
                                              const float* __restrict__ z0,
                                              _Float16* __restrict__ aH,
                                              _Float16* __restrict__ aL) {
  int g = blockIdx.x * 256 + threadIdx.x;  // 0 .. 2M-1
  int b = g >> 9;
  int k8 = (g & 511) * 8;

  const float4* pi = reinterpret_cast<const float4*>(&inputs[(size_t)b * 4096 + k8]);
  float4 x = pi[0], y = pi[1];
  float xs[8] = {x.x, x.y, x.z, x.w, y.x, y.y, y.z, y.w};
  f16x8 h, l;
#pragma unroll
  for (int i = 0; i < 8; ++i) {
    _Float16 hi = (_Float16)xs[i];
    h[i] = hi;
    l[i] = (_Float16)(xs[i] - (float)hi);
  }
  *reinterpret_cast<f16x8*>(&aH[(size_t)b * 8192 + k8]) = h;
  *reinterpret_cast<f16x8*>(&aL[(size_t)b * 4096 + k8]) = l;

  const float4* pz = reinterpret_cast<const float4*>(&z0[(size_t)b * 4096 + k8]);
  x = pz[0]; y = pz[1];
  float zs[8] = {x.x, x.y, x.z, x.w, y.x, y.y, y.z, y.w};
  f16x8 hz;
#pragma unroll
  for (int i = 0; i < 8; ++i) hz[i] = (_Float16)zs[i];
  *reinterpret_cast<f16x8*>(&aH[(size_t)b * 8192 + 4096 + k8]) = hz;
}

// ---------------------------------------------------------------------------
// lif_gemm: 256x256 tile, 8-phase schedule, single f32 acc -> S into outv.
// LDS map (131072 B dynamic): buf b: A at b*65536 + half*16384,
//                             B at b*65536 + 32768 + half*16384.
// ---------------------------------------------------------------------------
#define DO_MFMA(AF, BF, MH, NH)                                              \
  __builtin_amdgcn_s_setprio(1);                                             \
  _Pragma("unroll")                                                          \
  for (int j_ = 0; j_ < 4; ++j_)                                             \
    _Pragma("unroll")                                                        \
    for (int i_ = 0; i_ < 2; ++i_)                                           \
      _Pragma("unroll")                                                      \
      for (int kh_ = 0; kh_ < 2; ++kh_)                                      \
        acc[MH][j_][NH][i_] = __builtin_amdgcn_mfma_f32_16x16x32_f16(        \
            AF[j_][kh_], BF[i_][kh_], acc[MH][j_][NH][i_], 0, 0, 0);         \
  __builtin_amdgcn_s_setprio(0);

__global__ __launch_bounds__(512, 2) void lif_gemm(const _Float16* __restrict__ aH,
                                                   const _Float16* __restrict__ aL,
                                                   const _Float16* __restrict__ wtH,
                                                   const _Float16* __restrict__ wtL,
                                                   float* __restrict__ Sout) {
  extern __shared__ __align__(16) char lds[];

  int bid = blockIdx.x;
  int swz = (bid & 7) * 32 + (bid >> 3);  // XCD swizzle, bijective (256%8==0)
  int bm = swz >> 4, bn = swz & 15;
  int row0 = bm << 8, col0 = bn << 8;

  int t = threadIdx.x;
  int w = t >> 6, lane = t & 63;
  int wm = w >> 2, wn = w & 3;
  int wm16 = wm << 4, wn16 = wn << 4;
  int rl = lane & 15, klane = lane >> 4;
  int lr = lane >> 3;         // row within 8-row staging chunk
  int sg = (lane & 7) ^ lr;   // pre-swizzled source 16B group

  f32x4 acc[2][4][2][2];
#pragma unroll
  for (int a = 0; a < 2; ++a)
#pragma unroll
    for (int b = 0; b < 4; ++b)
#pragma unroll
      for (int c = 0; c < 2; ++c)
#pragma unroll
        for (int d = 0; d < 2; ++d) acc[a][b][c][d] = (f32x4){0.f, 0.f, 0.f, 0.f};

  auto stageA = [&](int buf, int half, const _Float16* A, int strA, int kb) {
#pragma unroll
    for (int c = 0; c < 2; ++c) {
      int gr = row0 + (half << 7) + (w << 4) + (c << 3) + lr;
      const char* src = (const char*)A + (((size_t)gr * strA + kb) << 1) + (sg << 4);
      char* dst = lds + (buf << 16) + (half << 14) + ((w * 2 + c) << 10);
      gl2lds16(src, dst);
    }
  };
  auto stageB = [&](int buf, int half, const _Float16* Bp, int kb) {
#pragma unroll
    for (int c = 0; c < 2; ++c) {
      int gc = col0 + (half << 7) + (w << 4) + (c << 3) + lr;
      const char* src = (const char*)Bp + (((size_t)gc * 8192 + kb) << 1) + (sg << 4);
      char* dst = lds + (buf << 16) + 32768 + (half << 14) + ((w * 2 + c) << 10);
      gl2lds16(src, dst);
    }
  };
  auto ldsFragA = [&](int buf, int half, int j, int kh) -> f16x8 {
    int r = (j << 5) + wm16 + rl;
    int kb = (kh << 6) + (klane << 4);
    int byte = (buf << 16) + (half << 14) + (r << 7) + (kb ^ ((r & 7) << 4));
    return *(const f16x8*)(lds + byte);
  };
  auto ldsFragB = [&](int buf, int half, int i, int kh) -> f16x8 {
    int r = (i << 6) + wn16 + rl;
    int kb = (kh << 6) + (klane << 4);
    int byte = (buf << 16) + 32768 + (half << 14) + (r << 7) + (kb ^ ((r & 7) << 4));
    return *(const f16x8*)(lds + byte);
  };
  auto segOf = [&](int tt, const _Float16*& A, const _Float16*& Bp, int& kb, int& strA) {
    if (tt < 128)      { A = aH; Bp = wtH; kb = tt << 6;         strA = 8192; }
    else if (tt < 256) { A = aH; Bp = wtL; kb = (tt - 128) << 6; strA = 8192; }
    else               { A = aL; Bp = wtH; kb = (tt - 256) << 6; strA = 4096; }
  };

  // prologue: stage tile 0 (A0,A1,B0,B1); allow B1 to stay in flight
  {
    const _Float16 *A, *Bp; int kb, strA;
    segOf(0, A, Bp, kb, strA);
    stageA(0, 0, A, strA, kb);
    stageA(0, 1, A, strA, kb);
    stageB(0, 0, Bp, kb);
    stageB(0, 1, Bp, kb);
  }
  WAITV(2);
  BAR();

  f16x8 a0f[4][2], a1f[4][2], b0f[2][2], b1f[2][2];

  for (int tau = 0; tau < 320; ++tau) {
    int cur = tau & 1, nxt = cur ^ 1;
    int nt = tau + 1;
    bool hn = nt < 320;
    const _Float16 *An = aH, *Bn = wtH; int kbn = 0, strAn = 8192;
    if (hn) segOf(nt, An, Bn, kbn, strAn);

    // ---- P0: quadrant (0,0); stage next A-half0
#pragma unroll
    for (int j = 0; j < 4; ++j)
#pragma unroll
      for (int kh = 0; kh < 2; ++kh) a0f[j][kh] = ldsFragA(cur, 0, j, kh);
#pragma unroll
    for (int i = 0; i < 2; ++i)
#pragma unroll
      for (int kh = 0; kh < 2; ++kh) b0f[i][kh] = ldsFragB(cur, 0, i, kh);
    if (hn) stageA(nxt, 0, An, strAn, kbn);
    BAR();
    DO_MFMA(a0f, b0f, 0, 0);
    BAR();

    // ---- P1: quadrant (1,0); stage next A-half1
#pragma unroll
    for (int j = 0; j < 4; ++j)
#pragma unroll
      for (int kh = 0; kh < 2; ++kh) a1f[j][kh] = ldsFragA(cur, 1, j, kh);
    if (hn) stageA(nxt, 1, An, strAn, kbn);
    BAR();
    DO_MFMA(a1f, b0f, 1, 0);
    if (tau == 319) { WAITV(0); } else { WAITV(4); }  // B-half1(cur) landed
    BAR();

    // ---- P2: quadrant (0,1); stage next B-half0
#pragma unroll
    for (int i = 0; i < 2; ++i)
#pragma unroll
      for (int kh = 0; kh < 2; ++kh) b1f[i][kh] = ldsFragB(cur, 1, i, kh);
    if (hn) stageB(nxt, 0, Bn, kbn);
    BAR();
    DO_MFMA(a0f, b1f, 0, 1);
    BAR();

    // ---- P3: quadrant (1,1); stage next B-half1
    if (hn) stageB(nxt, 1, Bn, kbn);
    BAR();
    DO_MFMA(a1f, b1f, 1, 1);
    if (hn) { WAITV(2); }  // next tile's A0,A1,B0 landed; B1 may fly
    BAR();
  }

  // write raw S = acc/256 (C/D: col = lane&15, row = (lane>>4)*4 + jj)
  const float invW = 1.0f / 256.0f;
#pragma unroll
  for (int mh = 0; mh < 2; ++mh)
#pragma unroll
    for (int j = 0; j < 4; ++j)
#pragma unroll
      for (int nh = 0; nh < 2; ++nh)
#pragma unroll
        for (int i = 0; i < 2; ++i) {
          int row = row0 + (mh << 7) + (j << 5) + wm16 + (klane << 2);
          int col = col0 + (nh << 7) + (i << 6) + wn16 + rl;
#pragma unroll
          for (int jj = 0; jj < 4; ++jj)
            Sout[(size_t)(row + jj) * 4096 + col] = acc[mh][j][nh][i][jj] * invW;
        }
}

// ---------------------------------------------------------------------------
// epilogue: elementwise LIF update, S read in place from outv.
// ---------------------------------------------------------------------------
__global__ __launch_bounds__(256) void lif_epilogue(const float* __restrict__ v0,
                                                    const int* __restrict__ r0,
                                                    const float* __restrict__ z0,
                                                    float* __restrict__ outv,
                                                    float* __restrict__ outz,
                                                    float* __restrict__ outr) {
  size_t i = ((size_t)blockIdx.x * 256 + threadIdx.x) * 4;
  float4 S = *reinterpret_cast<const float4*>(&outv[i]);
  float4 V = *reinterpret_cast<const float4*>(&v0[i]);
  float4 Z = *reinterpret_cast<const float4*>(&z0[i]);
  int4 R = *reinterpret_cast<const int4*>(&r0[i]);
  float s[4] = {S.x, S.y, S.z, S.w};
  float v[4] = {V.x, V.y, V.z, V.w};
  float z[4] = {Z.x, Z.y, Z.z, Z.w};
  int r[4] = {R.x, R.y, R.z, R.w};
  float4 ov, oz, orr;
  float* po[3] = {&ov.x, &oz.x, &orr.x};
#pragma unroll
  for (int j = 0; j < 4; ++j) {
    float nv = DECAY_F * v[j] + (ONEMD_F * s[j] - z[j]);
    bool spike = (nv > 1.0f) && (r[j] <= 0);
    int nr = r[j] - 1 + (spike ? 5 : 0);
    nr = nr < 0 ? 0 : (nr > 5 ? 5 : nr);
    po[0][j] = nv;
    po[1][j] = spike ? 1.0f : 0.0f;
    po[2][j] = (float)nr;
  }
  *reinterpret_cast<float4*>(&outv[i]) = ov;
  *reinterpret_cast<float4*>(&outz[i]) = oz;
  *reinterpret_cast<float4*>(&outr[i]) = orr;
}

// ---------------------------------------------------------------------------
extern "C" void kernel_launch(void* const* d_in, const int* in_sizes, int n_in,
                              void* d_out, int out_size, void* d_ws, size_t ws_size,
                              hipStream_t stream) {
  const float* inputs = (const float*)d_in[0];
  const float* v0     = (const float*)d_in[1];
  const int*   r0     = (const int*)d_in[2];
  const float* z0     = (const float*)d_in[3];
  const float* w_in   = (const float*)d_in[4];
  const float* w_rec  = (const float*)d_in[5];

  const size_t planeW = (size_t)4096 * 8192;  // f16 elements per weight plane
  if (ws_size < planeW * 2 * sizeof(_Float16)) return;  // need 128 MB (proven)

  _Float16* wtH = (_Float16*)d_ws;
  _Float16* wtL = wtH + planeW;

  float* out  = (float*)d_out;
  float* outv = out;                               // S, then new_v
  float* outz = out + (size_t)4096 * 4096;         // aH scratch, then new_z
  float* outr = out + (size_t)2 * 4096 * 4096;     // aL scratch, then new_r

  _Float16* aH = (_Float16*)outz;   // [4096][8192] f16 = 64 MB
  _Float16* aL = (_Float16*)outr;   // [4096][4096] f16 = 32 MB

  // allow 128 KiB dynamic LDS (ignore error; harmless if already set)
  (void)hipFuncSetAttribute((const void*)lif_gemm,
                            hipFuncAttributeMaxDynamicSharedMemorySize, 131072);

  prep_w<<<dim3(8192), dim3(256), 0, stream>>>(w_in, w_rec, wtH, wtL);
  prep_a<<<dim3(8192), dim3(256), 0, stream>>>(inputs, z0, aH, aL);
  lif_gemm<<<dim3(256), dim3(512), 131072, stream>>>(aH, aL, wtH, wtL, outv);
  lif_epilogue<<<dim3(16384), dim3(256), 0, stream>>>(v0, r0, z0, outv, outz, outr);
}